// Round 2
// baseline (832.460 us; speedup 1.0000x reference)
//
#include <hip/hip_runtime.h>
#include <math.h>

#define HWX 16384   // 128*128 pixels per (b, channel) plane

// ---------------------------------------------------------------------------
// Pack all six 5x5-conv weight sets into wpack[(ic*96 + o)*25 + k], o in [0,96):
//   o 0..17 pc1 | 18..35 pc2 | 36..53 pc4 | 54..71 pc5 | 72..80 z | 81..89 m
//   | 90..95 zero padding.  bias analogously in bpack[96].
// Source layout is OIHW: w[o][ic][ky][kx] -> o*1600 + ic*25 + k.
// ---------------------------------------------------------------------------
__global__ __launch_bounds__(256) void pack_kernel(
    const float* __restrict__ w1, const float* __restrict__ b1,
    const float* __restrict__ w2, const float* __restrict__ b2,
    const float* __restrict__ w4, const float* __restrict__ b4,
    const float* __restrict__ w5, const float* __restrict__ b5,
    const float* __restrict__ wz, const float* __restrict__ bz,
    const float* __restrict__ wm, const float* __restrict__ bm,
    float* __restrict__ wpack, float* __restrict__ bpack)
{
    const int idx = blockIdx.x * 256 + threadIdx.x;
    if (idx < 96) {
        const int o = idx; float v = 0.f;
        if      (o < 18) v = b1[o];
        else if (o < 36) v = b2[o - 18];
        else if (o < 54) v = b4[o - 36];
        else if (o < 72) v = b5[o - 54];
        else if (o < 81) v = bz[o - 72];
        else if (o < 90) v = bm[o - 81];
        bpack[o] = v;
    }
    if (idx < 64 * 96 * 25) {
        const int k    = idx % 25;
        const int rest = idx / 25;
        const int o    = rest % 96;
        const int ic   = rest / 96;
        const int off  = ic * 25 + k;
        float v = 0.f;
        if      (o < 18) v = w1[o * 1600 + off];
        else if (o < 36) v = w2[(o - 18) * 1600 + off];
        else if (o < 54) v = w4[(o - 36) * 1600 + off];
        else if (o < 72) v = w5[(o - 54) * 1600 + off];
        else if (o < 81) v = wz[(o - 72) * 1600 + off];
        else if (o < 90) v = wm[(o - 81) * 1600 + off];
        wpack[idx] = v;
    }
}

// ---------------------------------------------------------------------------
// Combined 5x5 conv (pad=2, IC=64) for ALL 96 packed output channels.
// grid (256 px-tiles of 8x8, 2 batches, 3 oc-groups of 32), block 256.
// Thread t: pixel px = t&63 of the tile, oc sub-group q = t>>6 (wave-uniform
// -> weight reads are scalar s_loads), 8 accumulators.
// IC staged 8 at a time -> 16 barriers total.
// ---------------------------------------------------------------------------
__global__ __launch_bounds__(256) void conv_all_kernel(
    const float* __restrict__ src, const float* __restrict__ wpack,
    const float* __restrict__ bpack,
    float* __restrict__ offs,    // [4][2][18][HWX]
    float* __restrict__ zbuf,    // [2][9][HWX]
    float* __restrict__ mbuf)    // [2][9][HWX]
{
    const int tt = blockIdx.x;
    const int b  = blockIdx.y;
    const int g  = blockIdx.z;
    const int y0 = (tt >> 4) << 3;
    const int x0 = (tt & 15) << 3;
    const int t   = threadIdx.x;
    const int px  = t & 63;
    const int q   = t >> 6;          // wave id -> oc sub-group
    const int py  = px >> 3, pxx = px & 7;
    const int oc0 = g * 32 + q * 8;

    __shared__ float tile_s[8][144];   // 8 ic x (12x12 halo tile)

    float acc[8];
    #pragma unroll
    for (int j = 0; j < 8; ++j) acc[j] = 0.f;

    for (int ic0 = 0; ic0 < 64; ic0 += 8) {
        __syncthreads();   // protect previous chunk's reads
        for (int idx = t; idx < 1152; idx += 256) {
            const int icl = idx / 144, rem = idx - icl * 144;
            const int ry = rem / 12, rx = rem - ry * 12;
            const int yy = y0 - 2 + ry, xx = x0 - 2 + rx;
            float v = 0.f;
            if (yy >= 0 && yy < 128 && xx >= 0 && xx < 128)
                v = src[(((b << 6) + ic0 + icl) << 14) + (yy << 7) + xx];
            tile_s[icl][rem] = v;
        }
        __syncthreads();
        for (int icl = 0; icl < 8; ++icl) {
            float r[25];
            #pragma unroll
            for (int ky = 0; ky < 5; ++ky)
                #pragma unroll
                for (int kx = 0; kx < 5; ++kx)
                    r[ky * 5 + kx] = tile_s[icl][(py + ky) * 12 + pxx + kx];
            const float* wb = wpack + (((ic0 + icl) * 96) + oc0) * 25;
            #pragma unroll
            for (int j = 0; j < 8; ++j) {
                const float* wj = wb + j * 25;
                #pragma unroll
                for (int k = 0; k < 25; ++k)
                    acc[j] = fmaf(wj[k], r[k], acc[j]);
            }
        }
    }

    const int p = ((y0 + py) << 7) + x0 + pxx;
    #pragma unroll
    for (int j = 0; j < 8; ++j) {
        const int o = oc0 + j;
        const float v = acc[j] + bpack[o];
        if (o < 72) {
            const int i = o / 18, ch = o - i * 18;
            offs[i * (2 * 18 * HWX) + (((b * 18) + ch) << 14) + p] = v;
        } else if (o < 81) {
            zbuf[((b * 9 + (o - 72)) << 14) + p] = 3.f / (1.f + expf(-v));
        } else if (o < 90) {
            mbuf[((b * 9 + (o - 81)) << 14) + p] = 1.f / (1.f + expf(-v));
        }
        // o >= 90: padding channel, discard
    }
}

// ---------------------------------------------------------------------------
// Transpose img[b,c,y,x] -> imgT[img][b][p][c]  (channel-last for coalesced
// gathers in the fused kernel). grid (256 p-tiles, B=2, 4 images), block 256.
// ---------------------------------------------------------------------------
__global__ __launch_bounds__(256) void transpose_kernel(
    const float* __restrict__ i0, const float* __restrict__ i1,
    const float* __restrict__ i2, const float* __restrict__ i3,
    float* __restrict__ imgT)
{
    const int img = blockIdx.z;
    const int b   = blockIdx.y;
    const int p0  = blockIdx.x << 6;
    const float* src = (img == 0) ? i0 : (img == 1) ? i1 : (img == 2) ? i2 : i3;

    __shared__ float tile[64][65];
    const int t = threadIdx.x;
    const int pp = t & 63, c0 = t >> 6;
    #pragma unroll
    for (int k = 0; k < 16; ++k) {
        const int c = (k << 2) + c0;
        tile[c][pp] = src[(((b << 6) + c) << 14) + p0 + pp];
    }
    __syncthreads();
    const int c = t & 63, pl = t >> 6;
    #pragma unroll
    for (int k = 0; k < 16; ++k) {
        const int pi = (k << 2) + pl;
        imgT[((((img << 1) + b) << 14) + p0 + pi) * 64 + c] = tile[c][pi];
    }
}

// ---------------------------------------------------------------------------
// WcT[(c*9+n)*64 + o] = w_conv[o,c,n]  (coalesced-over-o layout for phase C)
// ---------------------------------------------------------------------------
__global__ __launch_bounds__(256) void wct_kernel(
    const float* __restrict__ wc, float* __restrict__ WcT)
{
    const int idx = blockIdx.x * 256 + threadIdx.x;   // 36864 total
    if (idx < 36864) {
        const int cn = idx >> 6;
        const int o  = idx & 63;
        WcT[idx] = wc[o * 576 + cn];
    }
}

// ---------------------------------------------------------------------------
// Fused deform-sample + weighted-sum + final contraction.
// One block = 16 consecutive pixels of one row of one batch.
// ---------------------------------------------------------------------------
__global__ __launch_bounds__(256) void fused_kernel(
    const float* __restrict__ offs,   // [4][2][18][HWX]
    const float* __restrict__ zbuf,   // [2][9][HWX]
    const float* __restrict__ mbuf,   // [2][9][HWX]
    const float* __restrict__ imgT,   // [4][2][HWX][64]
    const float* __restrict__ WcT,    // [576][64]
    float* __restrict__ out)          // [2][64][HWX]
{
    __shared__ __align__(16) float s_s[16 * 576];    // 36864 B
    __shared__ int4   s_ti4[16 * 36];                // 9216 B
    __shared__ float4 s_tw4[16 * 36];                // 9216 B

    const int t   = threadIdx.x;
    const int pid = blockIdx.x;          // 2048 blocks
    const int b   = pid >> 10;
    const int rem = pid & 1023;
    const int h   = rem >> 3;
    const int w0p = (rem & 7) << 4;

    // ---- phase A: taps ----
    for (int u = t; u < 576; u += 256) {
        const int px   = u / 36;
        const int unit = u - px * 36;
        const int i    = unit / 9;
        const int n    = unit - i * 9;
        const int wcol = w0p + px;
        const int p    = (h << 7) + wcol;

        const float* ob = offs + i * (2 * 18 * HWX) + ((b * 18) << 14);
        const float ox = ob[(n << 14) + p];
        const float oy = ob[((n + 9) << 14) + p];
        const float z  = zbuf[((b * 9 + n) << 14) + p];
        const float mm = mbuf[((b * 9 + n) << 14) + p];

        const float zc0 = (i == 0) ? 1.f : 0.f;
        const float zc1 = (i == 0) ? (-11.f / 6.f) : (i == 1) ? 3.f
                         : (i == 2) ? -1.5f : (1.f / 3.f);
        const float zc2 = (i == 0) ? 1.f : (i == 1) ? -2.5f
                         : (i == 2) ? 2.f : -0.5f;
        const float zc3 = (i == 0) ? (-1.f / 6.f) : (i == 1) ? 0.5f
                         : (i == 2) ? -0.5f : (1.f / 6.f);
        const float zw   = zc0 + z * (zc1 + z * (zc2 + z * zc3));
        const float coef = zw * mm;

        const float pxf = (float)(h + n / 3) + ox;
        const float pyf = (float)(wcol + n % 3) + oy;
        const float flx = floorf(pxf), fly = floorf(pyf);
        const float qltx = fminf(fmaxf(flx, 0.f), 129.f);
        const float qrbx = fminf(fmaxf(flx + 1.f, 0.f), 129.f);
        const float qlty = fminf(fmaxf(fly, 0.f), 129.f);
        const float qrby = fminf(fmaxf(fly + 1.f, 0.f), 129.f);
        const float pxc = fminf(fmaxf(pxf, 0.f), 129.f);
        const float pyc = fminf(fmaxf(pyf, 0.f), 129.f);
        const float gxl = 1.f + (qltx - pxc);
        const float gxr = 1.f - (qrbx - pxc);
        const float gyl = 1.f + (qlty - pyc);
        const float gyr = 1.f - (qrby - pyc);
        const int ixl = (int)qltx, ixr = (int)qrbx;
        const int iyl = (int)qlty, iyr = (int)qrby;

        int4 ti; float4 tw;
        auto mk = [&](int qx, int qy, float g, int& ii, float& ww) {
            const bool valid = (qx >= 1) && (qx <= 128) && (qy >= 1) && (qy <= 128);
            ii = valid ? (((qx - 1) << 7) + (qy - 1)) : 0;
            ww = valid ? g * coef : 0.f;
        };
        mk(ixl, iyl, gxl * gyl, ti.x, tw.x);
        mk(ixr, iyr, gxr * gyr, ti.y, tw.y);
        mk(ixr, iyl, gxr * gyl, ti.z, tw.z);
        mk(ixl, iyr, gxl * gyr, ti.w, tw.w);
        s_ti4[u] = ti;
        s_tw4[u] = tw;
    }
    __syncthreads();

    // ---- phase B: sample s[px][c][n] ----
    const int c  = t & 63;
    const int wv = t >> 6;
    #pragma unroll 1
    for (int q = 0; q < 4; ++q) {
        const int px = (wv << 2) + q;
        float s[9];
        #pragma unroll
        for (int n = 0; n < 9; ++n) s[n] = 0.f;
        const int tb = px * 36;
        #pragma unroll
        for (int i = 0; i < 4; ++i) {
            const float* ib = imgT + ((((i << 1) + b) << 14) << 6) + c;
            #pragma unroll
            for (int n = 0; n < 9; ++n) {
                const int4   ti = s_ti4[tb + i * 9 + n];
                const float4 tw = s_tw4[tb + i * 9 + n];
                s[n] = fmaf(tw.x, ib[ti.x << 6], s[n]);
                s[n] = fmaf(tw.y, ib[ti.y << 6], s[n]);
                s[n] = fmaf(tw.z, ib[ti.z << 6], s[n]);
                s[n] = fmaf(tw.w, ib[ti.w << 6], s[n]);
            }
        }
        float* sp = s_s + px * 576 + c * 9;
        #pragma unroll
        for (int n = 0; n < 9; ++n) sp[n] = s[n];
    }
    __syncthreads();

    // ---- phase C: contraction out[o, px] ----
    const int o = t & 63;
    float acc0 = 0.f, acc1 = 0.f, acc2 = 0.f, acc3 = 0.f;
    const float* s0 = s_s + ((wv << 2) + 0) * 576;
    const float* s1 = s_s + ((wv << 2) + 1) * 576;
    const float* s2 = s_s + ((wv << 2) + 2) * 576;
    const float* s3 = s_s + ((wv << 2) + 3) * 576;
    #pragma unroll 2
    for (int cn = 0; cn < 576; cn += 4) {
        const float wv0 = WcT[(cn + 0) * 64 + o];
        const float wv1 = WcT[(cn + 1) * 64 + o];
        const float wv2 = WcT[(cn + 2) * 64 + o];
        const float wv3 = WcT[(cn + 3) * 64 + o];
        const float4 a = *(const float4*)(s0 + cn);
        const float4 e = *(const float4*)(s1 + cn);
        const float4 f = *(const float4*)(s2 + cn);
        const float4 g = *(const float4*)(s3 + cn);
        acc0 = fmaf(wv0, a.x, acc0); acc0 = fmaf(wv1, a.y, acc0);
        acc0 = fmaf(wv2, a.z, acc0); acc0 = fmaf(wv3, a.w, acc0);
        acc1 = fmaf(wv0, e.x, acc1); acc1 = fmaf(wv1, e.y, acc1);
        acc1 = fmaf(wv2, e.z, acc1); acc1 = fmaf(wv3, e.w, acc1);
        acc2 = fmaf(wv0, f.x, acc2); acc2 = fmaf(wv1, f.y, acc2);
        acc2 = fmaf(wv2, f.z, acc2); acc2 = fmaf(wv3, f.w, acc2);
        acc3 = fmaf(wv0, g.x, acc3); acc3 = fmaf(wv1, g.y, acc3);
        acc3 = fmaf(wv2, g.z, acc3); acc3 = fmaf(wv3, g.w, acc3);
    }

    // ---- phase D: staged coalesced store ----
    float* s_out = (float*)s_tw4;
    s_out[o * 17 + (wv << 2) + 0] = acc0;
    s_out[o * 17 + (wv << 2) + 1] = acc1;
    s_out[o * 17 + (wv << 2) + 2] = acc2;
    s_out[o * 17 + (wv << 2) + 3] = acc3;
    __syncthreads();
    #pragma unroll
    for (int k = 0; k < 4; ++k) {
        const int idx = t + (k << 8);
        const int oo  = idx >> 4;
        const int pxl = idx & 15;
        out[(((b << 6) + oo) << 14) + (h << 7) + w0p + pxl] = s_out[oo * 17 + pxl];
    }
}

// ---------------------------------------------------------------------------
extern "C" void kernel_launch(void* const* d_in, const int* in_sizes, int n_in,
                              void* d_out, int out_size, void* d_ws, size_t ws_size,
                              hipStream_t stream) {
    (void)in_sizes; (void)n_in; (void)out_size; (void)ws_size;
    const float* img1  = (const float*)d_in[0];
    const float* img2  = (const float*)d_in[1];
    const float* img4  = (const float*)d_in[2];
    const float* img5  = (const float*)d_in[3];
    const float* osrc  = (const float*)d_in[4];
    const float* w_pc1 = (const float*)d_in[5];
    const float* b_pc1 = (const float*)d_in[6];
    const float* w_pc2 = (const float*)d_in[7];
    const float* b_pc2 = (const float*)d_in[8];
    const float* w_pc4 = (const float*)d_in[9];
    const float* b_pc4 = (const float*)d_in[10];
    const float* w_pc5 = (const float*)d_in[11];
    const float* b_pc5 = (const float*)d_in[12];
    const float* w_z   = (const float*)d_in[13];
    const float* b_z   = (const float*)d_in[14];
    const float* w_m   = (const float*)d_in[15];
    const float* b_m   = (const float*)d_in[16];
    const float* w_cv  = (const float*)d_in[17];
    float* out = (float*)d_out;

    float* wsf  = (float*)d_ws;
    float* offs = wsf;                    // 4 * 589824 floats
    float* zbuf = wsf + 4 * 589824;       // 294912
    float* mbuf = zbuf + 294912;          // 294912
    float* WcT  = mbuf + 294912;          // 36864
    float* imgT = WcT + 36864;            // 8388608

    // wpack/bpack ALIAS the imgT region: pack+conv_all complete (stream order)
    // before transpose_kernel overwrites imgT.
    float* wpack = imgT;                  // 153600 floats
    float* bpack = imgT + 153600;         // 96

    pack_kernel<<<dim3((64 * 96 * 25 + 255) / 256), 256, 0, stream>>>(
        w_pc1, b_pc1, w_pc2, b_pc2, w_pc4, b_pc4, w_pc5, b_pc5,
        w_z, b_z, w_m, b_m, wpack, bpack);
    conv_all_kernel<<<dim3(256, 2, 3), 256, 0, stream>>>(
        osrc, wpack, bpack, offs, zbuf, mbuf);
    transpose_kernel<<<dim3(256, 2, 4), 256, 0, stream>>>(img1, img2, img4, img5, imgT);
    wct_kernel<<<dim3(144), 256, 0, stream>>>(w_cv, WcT);
    fused_kernel<<<dim3(2048), 256, 0, stream>>>(offs, zbuf, mbuf, imgT, WcT, out);
}

// Round 3
// 372.403 us; speedup vs baseline: 2.2354x; 2.2354x over previous
//
#include <hip/hip_runtime.h>
#include <math.h>

#define HWX 16384   // 128*128 pixels per (b, channel) plane

// ---------------------------------------------------------------------------
// Pack six 5x5-conv weight sets into wpack2[(ic*25 + k)*96 + o]:
//   o 0..17 pc1 | 18..35 pc2 | 36..53 pc4 | 54..71 pc5 | 72..80 z | 81..89 m
//   | 90..95 zero.  bias in bpack[96].  Source OIHW: w[o][ic][k].
// ---------------------------------------------------------------------------
__global__ __launch_bounds__(256) void pack_kernel(
    const float* __restrict__ w1, const float* __restrict__ b1,
    const float* __restrict__ w2, const float* __restrict__ b2,
    const float* __restrict__ w4, const float* __restrict__ b4,
    const float* __restrict__ w5, const float* __restrict__ b5,
    const float* __restrict__ wz, const float* __restrict__ bz,
    const float* __restrict__ wm, const float* __restrict__ bm,
    float* __restrict__ wpack, float* __restrict__ bpack)
{
    const int idx = blockIdx.x * 256 + threadIdx.x;
    if (idx < 96) {
        const int o = idx; float v = 0.f;
        if      (o < 18) v = b1[o];
        else if (o < 36) v = b2[o - 18];
        else if (o < 54) v = b4[o - 36];
        else if (o < 72) v = b5[o - 54];
        else if (o < 81) v = bz[o - 72];
        else if (o < 90) v = bm[o - 81];
        bpack[o] = v;
    }
    if (idx < 64 * 25 * 96) {
        const int o    = idx % 96;
        const int rest = idx / 96;
        const int k    = rest % 25;
        const int ic   = rest / 25;
        const int off  = ic * 25 + k;
        float v = 0.f;
        if      (o < 18) v = w1[o * 1600 + off];
        else if (o < 36) v = w2[(o - 18) * 1600 + off];
        else if (o < 54) v = w4[(o - 36) * 1600 + off];
        else if (o < 72) v = w5[(o - 54) * 1600 + off];
        else if (o < 81) v = wz[(o - 72) * 1600 + off];
        else if (o < 90) v = wm[(o - 81) * 1600 + off];
        wpack[idx] = v;
    }
}

// ---------------------------------------------------------------------------
// Implicit-im2col GEMM conv, fp32, both operands in LDS, outer-product tile.
// Block: 32 oc x 256 px (16x16 tile).  Thread: 4 oc x 8 px (32 acc).
//   px_t = t&31 -> row r = px_t>>1, col-half c0 = (px_t&1)*8
//   oc_t = t>>5 -> ocs og*32 + oc_t*4 .. +3
// K staged in ic-chunks of 8: x_s[8][20][20] halo tile, w_s[8][25][32].
// grid (64 px-tiles, 2 b, 3 oc-groups), block 256.
// ---------------------------------------------------------------------------
__global__ __launch_bounds__(256) void conv_gemm_kernel(
    const float* __restrict__ src, const float* __restrict__ wpack,
    const float* __restrict__ bpack,
    float* __restrict__ offs,    // [4][2][18][HWX]
    float* __restrict__ zbuf,    // [2][9][HWX]
    float* __restrict__ mbuf)    // [2][9][HWX]
{
    const int tt = blockIdx.x;
    const int b  = blockIdx.y;
    const int og = blockIdx.z;
    const int y0 = (tt >> 3) << 4;
    const int x0 = (tt & 7) << 4;

    const int t    = threadIdx.x;
    const int px_t = t & 31;
    const int oc_t = t >> 5;
    const int r    = px_t >> 1;
    const int c0   = (px_t & 1) << 3;

    __shared__ float x_s[8][20][20];   // 12.8 KB
    __shared__ float w_s[8][25][32];   // 25.6 KB

    float acc[4][8];
    #pragma unroll
    for (int j = 0; j < 4; ++j)
        #pragma unroll
        for (int p = 0; p < 8; ++p) acc[j][p] = 0.f;

    for (int ic0 = 0; ic0 < 64; ic0 += 8) {
        __syncthreads();   // protect previous chunk's reads
        // stage pixels: 8 icl x 20x20 halo
        for (int idx = t; idx < 3200; idx += 256) {
            const int icl = idx / 400, rem = idx - icl * 400;
            const int ry = rem / 20, rx = rem - ry * 20;
            const int yy = y0 - 2 + ry, xx = x0 - 2 + rx;
            float v = 0.f;
            if (yy >= 0 && yy < 128 && xx >= 0 && xx < 128)
                v = src[(((b << 6) + ic0 + icl) << 14) + (yy << 7) + xx];
            x_s[icl][ry][rx] = v;
        }
        // stage weights: 8 icl x 25 k x 32 oc  (coalesced over oc)
        for (int idx = t; idx < 6400; idx += 256) {
            const int ol = idx & 31;
            const int rest = idx >> 5;
            const int kk = rest % 25, icl = rest / 25;
            w_s[icl][kk][ol] = wpack[(((ic0 + icl) * 25) + kk) * 96 + og * 32 + ol];
        }
        __syncthreads();

        for (int icl = 0; icl < 8; ++icl) {
            #pragma unroll
            for (int ky = 0; ky < 5; ++ky) {
                // 12 pixels covering all 5 kx windows of 8 px
                float xv[12];
                *(float4*)&xv[0] = *(const float4*)&x_s[icl][r + ky][c0];
                *(float4*)&xv[4] = *(const float4*)&x_s[icl][r + ky][c0 + 4];
                *(float4*)&xv[8] = *(const float4*)&x_s[icl][r + ky][c0 + 8];
                #pragma unroll
                for (int kx = 0; kx < 5; ++kx) {
                    const float4 wv = *(const float4*)&w_s[icl][ky * 5 + kx][oc_t << 2];
                    #pragma unroll
                    for (int p = 0; p < 8; ++p) {
                        const float xx = xv[p + kx];
                        acc[0][p] = fmaf(wv.x, xx, acc[0][p]);
                        acc[1][p] = fmaf(wv.y, xx, acc[1][p]);
                        acc[2][p] = fmaf(wv.z, xx, acc[2][p]);
                        acc[3][p] = fmaf(wv.w, xx, acc[3][p]);
                    }
                }
            }
        }
    }

    // epilogue: bias + activation + scatter to offs/z/m
    const int y = y0 + r;
    const int pbase = (y << 7) + x0 + c0;
    #pragma unroll
    for (int j = 0; j < 4; ++j) {
        const int o = og * 32 + (oc_t << 2) + j;
        const float bia = bpack[o];
        if (o < 72) {
            const int i = o / 18, ch = o - i * 18;
            float* dst = offs + i * (2 * 18 * HWX) + (((b * 18) + ch) << 14) + pbase;
            #pragma unroll
            for (int p = 0; p < 8; ++p) dst[p] = acc[j][p] + bia;
        } else if (o < 81) {
            float* dst = zbuf + ((b * 9 + (o - 72)) << 14) + pbase;
            #pragma unroll
            for (int p = 0; p < 8; ++p)
                dst[p] = 3.f / (1.f + expf(-(acc[j][p] + bia)));
        } else if (o < 90) {
            float* dst = mbuf + ((b * 9 + (o - 81)) << 14) + pbase;
            #pragma unroll
            for (int p = 0; p < 8; ++p)
                dst[p] = 1.f / (1.f + expf(-(acc[j][p] + bia)));
        }
        // o >= 90: padding, discard
    }
}

// ---------------------------------------------------------------------------
// Transpose img[b,c,y,x] -> imgT[img][b][p][c]
// ---------------------------------------------------------------------------
__global__ __launch_bounds__(256) void transpose_kernel(
    const float* __restrict__ i0, const float* __restrict__ i1,
    const float* __restrict__ i2, const float* __restrict__ i3,
    float* __restrict__ imgT)
{
    const int img = blockIdx.z;
    const int b   = blockIdx.y;
    const int p0  = blockIdx.x << 6;
    const float* src = (img == 0) ? i0 : (img == 1) ? i1 : (img == 2) ? i2 : i3;

    __shared__ float tile[64][65];
    const int t = threadIdx.x;
    const int pp = t & 63, c0 = t >> 6;
    #pragma unroll
    for (int k = 0; k < 16; ++k) {
        const int c = (k << 2) + c0;
        tile[c][pp] = src[(((b << 6) + c) << 14) + p0 + pp];
    }
    __syncthreads();
    const int c = t & 63, pl = t >> 6;
    #pragma unroll
    for (int k = 0; k < 16; ++k) {
        const int pi = (k << 2) + pl;
        imgT[((((img << 1) + b) << 14) + p0 + pi) * 64 + c] = tile[c][pi];
    }
}

// ---------------------------------------------------------------------------
// WcT[(c*9+n)*64 + o] = w_conv[o,c,n]
// ---------------------------------------------------------------------------
__global__ __launch_bounds__(256) void wct_kernel(
    const float* __restrict__ wc, float* __restrict__ WcT)
{
    const int idx = blockIdx.x * 256 + threadIdx.x;
    if (idx < 36864) {
        const int cn = idx >> 6;
        const int o  = idx & 63;
        WcT[idx] = wc[o * 576 + cn];
    }
}

// ---------------------------------------------------------------------------
// Fused deform-sample + weighted-sum + final contraction.
// ---------------------------------------------------------------------------
__global__ __launch_bounds__(256) void fused_kernel(
    const float* __restrict__ offs,   // [4][2][18][HWX]
    const float* __restrict__ zbuf,   // [2][9][HWX]
    const float* __restrict__ mbuf,   // [2][9][HWX]
    const float* __restrict__ imgT,   // [4][2][HWX][64]
    const float* __restrict__ WcT,    // [576][64]
    float* __restrict__ out)          // [2][64][HWX]
{
    __shared__ __align__(16) float s_s[16 * 576];
    __shared__ int4   s_ti4[16 * 36];
    __shared__ float4 s_tw4[16 * 36];

    const int t   = threadIdx.x;
    const int pid = blockIdx.x;
    const int b   = pid >> 10;
    const int rem = pid & 1023;
    const int h   = rem >> 3;
    const int w0p = (rem & 7) << 4;

    // ---- phase A: taps ----
    for (int u = t; u < 576; u += 256) {
        const int px   = u / 36;
        const int unit = u - px * 36;
        const int i    = unit / 9;
        const int n    = unit - i * 9;
        const int wcol = w0p + px;
        const int p    = (h << 7) + wcol;

        const float* ob = offs + i * (2 * 18 * HWX) + ((b * 18) << 14);
        const float ox = ob[(n << 14) + p];
        const float oy = ob[((n + 9) << 14) + p];
        const float z  = zbuf[((b * 9 + n) << 14) + p];
        const float mm = mbuf[((b * 9 + n) << 14) + p];

        const float zc0 = (i == 0) ? 1.f : 0.f;
        const float zc1 = (i == 0) ? (-11.f / 6.f) : (i == 1) ? 3.f
                         : (i == 2) ? -1.5f : (1.f / 3.f);
        const float zc2 = (i == 0) ? 1.f : (i == 1) ? -2.5f
                         : (i == 2) ? 2.f : -0.5f;
        const float zc3 = (i == 0) ? (-1.f / 6.f) : (i == 1) ? 0.5f
                         : (i == 2) ? -0.5f : (1.f / 6.f);
        const float zw   = zc0 + z * (zc1 + z * (zc2 + z * zc3));
        const float coef = zw * mm;

        const float pxf = (float)(h + n / 3) + ox;
        const float pyf = (float)(wcol + n % 3) + oy;
        const float flx = floorf(pxf), fly = floorf(pyf);
        const float qltx = fminf(fmaxf(flx, 0.f), 129.f);
        const float qrbx = fminf(fmaxf(flx + 1.f, 0.f), 129.f);
        const float qlty = fminf(fmaxf(fly, 0.f), 129.f);
        const float qrby = fminf(fmaxf(fly + 1.f, 0.f), 129.f);
        const float pxc = fminf(fmaxf(pxf, 0.f), 129.f);
        const float pyc = fminf(fmaxf(pyf, 0.f), 129.f);
        const float gxl = 1.f + (qltx - pxc);
        const float gxr = 1.f - (qrbx - pxc);
        const float gyl = 1.f + (qlty - pyc);
        const float gyr = 1.f - (qrby - pyc);
        const int ixl = (int)qltx, ixr = (int)qrbx;
        const int iyl = (int)qlty, iyr = (int)qrby;

        int4 ti; float4 tw;
        auto mk = [&](int qx, int qy, float g, int& ii, float& ww) {
            const bool valid = (qx >= 1) && (qx <= 128) && (qy >= 1) && (qy <= 128);
            ii = valid ? (((qx - 1) << 7) + (qy - 1)) : 0;
            ww = valid ? g * coef : 0.f;
        };
        mk(ixl, iyl, gxl * gyl, ti.x, tw.x);
        mk(ixr, iyr, gxr * gyr, ti.y, tw.y);
        mk(ixr, iyl, gxr * gyl, ti.z, tw.z);
        mk(ixl, iyr, gxl * gyr, ti.w, tw.w);
        s_ti4[u] = ti;
        s_tw4[u] = tw;
    }
    __syncthreads();

    // ---- phase B: sample s[px][c][n] ----
    const int c  = t & 63;
    const int wv = t >> 6;
    #pragma unroll 1
    for (int q = 0; q < 4; ++q) {
        const int px = (wv << 2) + q;
        float s[9];
        #pragma unroll
        for (int n = 0; n < 9; ++n) s[n] = 0.f;
        const int tb = px * 36;
        #pragma unroll
        for (int i = 0; i < 4; ++i) {
            const float* ib = imgT + ((((i << 1) + b) << 14) << 6) + c;
            #pragma unroll
            for (int n = 0; n < 9; ++n) {
                const int4   ti = s_ti4[tb + i * 9 + n];
                const float4 tw = s_tw4[tb + i * 9 + n];
                s[n] = fmaf(tw.x, ib[ti.x << 6], s[n]);
                s[n] = fmaf(tw.y, ib[ti.y << 6], s[n]);
                s[n] = fmaf(tw.z, ib[ti.z << 6], s[n]);
                s[n] = fmaf(tw.w, ib[ti.w << 6], s[n]);
            }
        }
        float* sp = s_s + px * 576 + c * 9;
        #pragma unroll
        for (int n = 0; n < 9; ++n) sp[n] = s[n];
    }
    __syncthreads();

    // ---- phase C: contraction out[o, px] ----
    const int o = t & 63;
    float acc0 = 0.f, acc1 = 0.f, acc2 = 0.f, acc3 = 0.f;
    const float* s0 = s_s + ((wv << 2) + 0) * 576;
    const float* s1 = s_s + ((wv << 2) + 1) * 576;
    const float* s2 = s_s + ((wv << 2) + 2) * 576;
    const float* s3 = s_s + ((wv << 2) + 3) * 576;
    #pragma unroll 2
    for (int cn = 0; cn < 576; cn += 4) {
        const float wv0 = WcT[(cn + 0) * 64 + o];
        const float wv1 = WcT[(cn + 1) * 64 + o];
        const float wv2 = WcT[(cn + 2) * 64 + o];
        const float wv3 = WcT[(cn + 3) * 64 + o];
        const float4 a = *(const float4*)(s0 + cn);
        const float4 e = *(const float4*)(s1 + cn);
        const float4 f = *(const float4*)(s2 + cn);
        const float4 g = *(const float4*)(s3 + cn);
        acc0 = fmaf(wv0, a.x, acc0); acc0 = fmaf(wv1, a.y, acc0);
        acc0 = fmaf(wv2, a.z, acc0); acc0 = fmaf(wv3, a.w, acc0);
        acc1 = fmaf(wv0, e.x, acc1); acc1 = fmaf(wv1, e.y, acc1);
        acc1 = fmaf(wv2, e.z, acc1); acc1 = fmaf(wv3, e.w, acc1);
        acc2 = fmaf(wv0, f.x, acc2); acc2 = fmaf(wv1, f.y, acc2);
        acc2 = fmaf(wv2, f.z, acc2); acc2 = fmaf(wv3, f.w, acc2);
        acc3 = fmaf(wv0, g.x, acc3); acc3 = fmaf(wv1, g.y, acc3);
        acc3 = fmaf(wv2, g.z, acc3); acc3 = fmaf(wv3, g.w, acc3);
    }

    // ---- phase D: staged coalesced store ----
    float* s_out = (float*)s_tw4;
    s_out[o * 17 + (wv << 2) + 0] = acc0;
    s_out[o * 17 + (wv << 2) + 1] = acc1;
    s_out[o * 17 + (wv << 2) + 2] = acc2;
    s_out[o * 17 + (wv << 2) + 3] = acc3;
    __syncthreads();
    #pragma unroll
    for (int k = 0; k < 4; ++k) {
        const int idx = t + (k << 8);
        const int oo  = idx >> 4;
        const int pxl = idx & 15;
        out[(((b << 6) + oo) << 14) + (h << 7) + w0p + pxl] = s_out[oo * 17 + pxl];
    }
}

// ---------------------------------------------------------------------------
extern "C" void kernel_launch(void* const* d_in, const int* in_sizes, int n_in,
                              void* d_out, int out_size, void* d_ws, size_t ws_size,
                              hipStream_t stream) {
    (void)in_sizes; (void)n_in; (void)out_size; (void)ws_size;
    const float* img1  = (const float*)d_in[0];
    const float* img2  = (const float*)d_in[1];
    const float* img4  = (const float*)d_in[2];
    const float* img5  = (const float*)d_in[3];
    const float* osrc  = (const float*)d_in[4];
    const float* w_pc1 = (const float*)d_in[5];
    const float* b_pc1 = (const float*)d_in[6];
    const float* w_pc2 = (const float*)d_in[7];
    const float* b_pc2 = (const float*)d_in[8];
    const float* w_pc4 = (const float*)d_in[9];
    const float* b_pc4 = (const float*)d_in[10];
    const float* w_pc5 = (const float*)d_in[11];
    const float* b_pc5 = (const float*)d_in[12];
    const float* w_z   = (const float*)d_in[13];
    const float* b_z   = (const float*)d_in[14];
    const float* w_m   = (const float*)d_in[15];
    const float* b_m   = (const float*)d_in[16];
    const float* w_cv  = (const float*)d_in[17];
    float* out = (float*)d_out;

    float* wsf  = (float*)d_ws;
    float* offs = wsf;                    // 4 * 589824 floats
    float* zbuf = wsf + 4 * 589824;       // 294912
    float* mbuf = zbuf + 294912;          // 294912
    float* WcT  = mbuf + 294912;          // 36864
    float* imgT = WcT + 36864;            // 8388608

    // wpack/bpack ALIAS the imgT region (pack+conv finish before transpose).
    float* wpack = imgT;                  // 153600 floats
    float* bpack = imgT + 153600;         // 96

    pack_kernel<<<dim3((64 * 25 * 96 + 255) / 256), 256, 0, stream>>>(
        w_pc1, b_pc1, w_pc2, b_pc2, w_pc4, b_pc4, w_pc5, b_pc5,
        w_z, b_z, w_m, b_m, wpack, bpack);
    conv_gemm_kernel<<<dim3(64, 2, 3), 256, 0, stream>>>(
        osrc, wpack, bpack, offs, zbuf, mbuf);
    transpose_kernel<<<dim3(256, 2, 4), 256, 0, stream>>>(img1, img2, img4, img5, imgT);
    wct_kernel<<<dim3(144), 256, 0, stream>>>(w_cv, WcT);
    fused_kernel<<<dim3(2048), 256, 0, stream>>>(offs, zbuf, mbuf, imgT, WcT, out);
}

// Round 4
// 280.293 us; speedup vs baseline: 2.9700x; 1.3286x over previous
//
#include <hip/hip_runtime.h>
#include <hip/hip_bf16.h>
#include <math.h>

#define HWX 16384   // 128*128 pixels per (b, channel) plane

typedef __attribute__((ext_vector_type(8))) short short8v;
typedef __attribute__((ext_vector_type(4))) float f32x4;

// ---------------------------------------------------------------------------
// Pack six 5x5-conv weight sets -> Wpk[oc][k] bf16, k = (ky*5+kx)*64 + ic.
//   oc 0..17 pc1 | 18..35 pc2 | 36..53 pc4 | 54..71 pc5 | 72..80 z | 81..89 m
//   | 90..95 zero.  bias fp32 in bpack[96].  Source OIHW: o*1600 + ic*25 + kyx.
// ---------------------------------------------------------------------------
__global__ __launch_bounds__(256) void packw_kernel(
    const float* __restrict__ w1, const float* __restrict__ b1,
    const float* __restrict__ w2, const float* __restrict__ b2,
    const float* __restrict__ w4, const float* __restrict__ b4,
    const float* __restrict__ w5, const float* __restrict__ b5,
    const float* __restrict__ wz, const float* __restrict__ bz,
    const float* __restrict__ wm, const float* __restrict__ bm,
    __hip_bfloat16* __restrict__ Wpk, float* __restrict__ bpack)
{
    const int idx = blockIdx.x * 256 + threadIdx.x;
    if (idx < 96) {
        const int o = idx; float v = 0.f;
        if      (o < 18) v = b1[o];
        else if (o < 36) v = b2[o - 18];
        else if (o < 54) v = b4[o - 36];
        else if (o < 72) v = b5[o - 54];
        else if (o < 81) v = bz[o - 72];
        else if (o < 90) v = bm[o - 81];
        bpack[o] = v;
    }
    if (idx < 96 * 1600) {
        const int o   = idx / 1600;
        const int k   = idx - o * 1600;
        const int kyx = k >> 6;
        const int ic  = k & 63;
        const int off = ic * 25 + kyx;
        float v = 0.f;
        if      (o < 18) v = w1[o * 1600 + off];
        else if (o < 36) v = w2[(o - 18) * 1600 + off];
        else if (o < 54) v = w4[(o - 36) * 1600 + off];
        else if (o < 72) v = w5[(o - 54) * 1600 + off];
        else if (o < 81) v = wz[(o - 72) * 1600 + off];
        else if (o < 90) v = wm[(o - 81) * 1600 + off];
        Wpk[idx] = __float2bfloat16(v);
    }
}

// ---------------------------------------------------------------------------
// offset_source -> channel-last bf16 with baked-in zero pad ring:
//   osT[b][yy:132][xx:132][c:64] = (in-bounds) ? bf16(src[b][c][yy-2][xx-2]) : 0
// grid (132, 2), block 256; per-block L1 temporal reuse keeps reads cheap.
// ---------------------------------------------------------------------------
__global__ __launch_bounds__(256) void packosT_kernel(
    const float* __restrict__ src, __hip_bfloat16* __restrict__ osT)
{
    const int yy = blockIdx.x;
    const int b  = blockIdx.y;
    __hip_bfloat16* dst = osT + ((size_t)b * 132 + yy) * 132 * 64;
    for (int idx = threadIdx.x; idx < 132 * 64; idx += 256) {
        const int xx = idx >> 6;
        const int c  = idx & 63;
        float v = 0.f;
        if (yy >= 2 && yy < 130 && xx >= 2 && xx < 130)
            v = src[(((b << 6) + c) << 14) + ((yy - 2) << 7) + (xx - 2)];
        dst[idx] = __float2bfloat16(v);
    }
}

// ---------------------------------------------------------------------------
// MFMA conv: C[96][16384] = Wpk[96][1600] x im2col(osT), per batch.
// No LDS, no barriers: A- and B-fragments are direct 16B global loads
// (k-contiguous thanks to (ky,kx)-major / ic-minor K ordering + channel-last osT).
// Block 256 = 4 waves; wave = 32 oc x 32 px; block = one image row (ocg of 32).
// grid (128 rows, 2 b, 3 ocg) = 768 blocks.
// ---------------------------------------------------------------------------
__global__ __launch_bounds__(256) void conv_mfma_kernel(
    const __hip_bfloat16* __restrict__ Wpk,   // [96][1600]
    const float* __restrict__ bpack,          // [96]
    const __hip_bfloat16* __restrict__ osT,   // [2][132][132][64]
    float* __restrict__ offs,                 // [4][2][18][HWX]
    float* __restrict__ zbuf,                 // [2][9][HWX]
    float* __restrict__ mbuf)                 // [2][9][HWX]
{
    const int y   = blockIdx.x;
    const int b   = blockIdx.y;
    const int ocg = blockIdx.z;
    const int t    = threadIdx.x;
    const int wv   = t >> 6;
    const int lane = t & 63;
    const int l15  = lane & 15;
    const int kgrp = lane >> 4;

    const ushort* W  = (const ushort*)Wpk;
    const ushort* ob = (const ushort*)osT + (size_t)b * (132 * 132 * 64);

    // lane-constant element offsets
    const int aoff0 = (ocg * 32 + l15) * 1600 + kgrp * 8;
    const int aoff1 = aoff0 + 16 * 1600;
    const int xloc0 = wv * 32 + l15;
    const int boff0 = (y * 132 + xloc0) * 64 + kgrp * 8;
    const int boff1 = boff0 + 16 * 64;

    f32x4 acc00 = {0.f,0.f,0.f,0.f}, acc01 = {0.f,0.f,0.f,0.f};
    f32x4 acc10 = {0.f,0.f,0.f,0.f}, acc11 = {0.f,0.f,0.f,0.f};

    #pragma unroll
    for (int ky = 0; ky < 5; ++ky)
    #pragma unroll
    for (int kx = 0; kx < 5; ++kx)
    #pragma unroll
    for (int ics = 0; ics < 2; ++ics) {
        const int uA = ((ky * 5 + kx) << 6) + (ics << 5);     // Wpk k-offset
        const int uB = ((ky * 132 + kx) << 6) + (ics << 5);   // osT offset
        const short8v a0 = *(const short8v*)(W  + aoff0 + uA);
        const short8v a1 = *(const short8v*)(W  + aoff1 + uA);
        const short8v b0 = *(const short8v*)(ob + boff0 + uB);
        const short8v b1 = *(const short8v*)(ob + boff1 + uB);
        acc00 = __builtin_amdgcn_mfma_f32_16x16x32_bf16(a0, b0, acc00, 0, 0, 0);
        acc01 = __builtin_amdgcn_mfma_f32_16x16x32_bf16(a0, b1, acc01, 0, 0, 0);
        acc10 = __builtin_amdgcn_mfma_f32_16x16x32_bf16(a1, b0, acc10, 0, 0, 0);
        acc11 = __builtin_amdgcn_mfma_f32_16x16x32_bf16(a1, b1, acc11, 0, 0, 0);
    }

    // epilogue: C/D layout col=lane&15 (px), row=(lane>>4)*4+r (oc)
    const int rowb = kgrp << 2;
    #pragma unroll
    for (int m = 0; m < 2; ++m)
    #pragma unroll
    for (int nf = 0; nf < 2; ++nf)
    #pragma unroll
    for (int r = 0; r < 4; ++r) {
        const f32x4 acc = (m == 0) ? (nf == 0 ? acc00 : acc01)
                                   : (nf == 0 ? acc10 : acc11);
        const int oc = ocg * 32 + m * 16 + rowb + r;
        if (oc < 90) {
            const int x = wv * 32 + nf * 16 + l15;
            const int p = (y << 7) + x;
            const float v = acc[r] + bpack[oc];
            if (oc < 72) {
                const int i = oc / 18, ch = oc - i * 18;
                offs[i * (2 * 18 * HWX) + (((b * 18) + ch) << 14) + p] = v;
            } else if (oc < 81) {
                zbuf[((b * 9 + (oc - 72)) << 14) + p] = 3.f / (1.f + expf(-v));
            } else {
                mbuf[((b * 9 + (oc - 81)) << 14) + p] = 1.f / (1.f + expf(-v));
            }
        }
    }
}

// ---------------------------------------------------------------------------
// Transpose img[b,c,y,x] -> imgT[img][b][p][c]
// ---------------------------------------------------------------------------
__global__ __launch_bounds__(256) void transpose_kernel(
    const float* __restrict__ i0, const float* __restrict__ i1,
    const float* __restrict__ i2, const float* __restrict__ i3,
    float* __restrict__ imgT)
{
    const int img = blockIdx.z;
    const int b   = blockIdx.y;
    const int p0  = blockIdx.x << 6;
    const float* src = (img == 0) ? i0 : (img == 1) ? i1 : (img == 2) ? i2 : i3;

    __shared__ float tile[64][65];
    const int t = threadIdx.x;
    const int pp = t & 63, c0 = t >> 6;
    #pragma unroll
    for (int k = 0; k < 16; ++k) {
        const int c = (k << 2) + c0;
        tile[c][pp] = src[(((b << 6) + c) << 14) + p0 + pp];
    }
    __syncthreads();
    const int c = t & 63, pl = t >> 6;
    #pragma unroll
    for (int k = 0; k < 16; ++k) {
        const int pi = (k << 2) + pl;
        imgT[((((img << 1) + b) << 14) + p0 + pi) * 64 + c] = tile[c][pi];
    }
}

// ---------------------------------------------------------------------------
// WcT[(c*9+n)*64 + o] = w_conv[o,c,n]
// ---------------------------------------------------------------------------
__global__ __launch_bounds__(256) void wct_kernel(
    const float* __restrict__ wc, float* __restrict__ WcT)
{
    const int idx = blockIdx.x * 256 + threadIdx.x;
    if (idx < 36864) {
        const int cn = idx >> 6;
        const int o  = idx & 63;
        WcT[idx] = wc[o * 576 + cn];
    }
}

// ---------------------------------------------------------------------------
// Fused deform-sample + weighted-sum + final contraction.
// ---------------------------------------------------------------------------
__global__ __launch_bounds__(256) void fused_kernel(
    const float* __restrict__ offs,   // [4][2][18][HWX]
    const float* __restrict__ zbuf,   // [2][9][HWX]
    const float* __restrict__ mbuf,   // [2][9][HWX]
    const float* __restrict__ imgT,   // [4][2][HWX][64]
    const float* __restrict__ WcT,    // [576][64]
    float* __restrict__ out)          // [2][64][HWX]
{
    __shared__ __align__(16) float s_s[16 * 576];
    __shared__ int4   s_ti4[16 * 36];
    __shared__ float4 s_tw4[16 * 36];

    const int t   = threadIdx.x;
    const int pid = blockIdx.x;
    const int b   = pid >> 10;
    const int rem = pid & 1023;
    const int h   = rem >> 3;
    const int w0p = (rem & 7) << 4;

    // ---- phase A: taps ----
    for (int u = t; u < 576; u += 256) {
        const int px   = u / 36;
        const int unit = u - px * 36;
        const int i    = unit / 9;
        const int n    = unit - i * 9;
        const int wcol = w0p + px;
        const int p    = (h << 7) + wcol;

        const float* ob = offs + i * (2 * 18 * HWX) + ((b * 18) << 14);
        const float ox = ob[(n << 14) + p];
        const float oy = ob[((n + 9) << 14) + p];
        const float z  = zbuf[((b * 9 + n) << 14) + p];
        const float mm = mbuf[((b * 9 + n) << 14) + p];

        const float zc0 = (i == 0) ? 1.f : 0.f;
        const float zc1 = (i == 0) ? (-11.f / 6.f) : (i == 1) ? 3.f
                         : (i == 2) ? -1.5f : (1.f / 3.f);
        const float zc2 = (i == 0) ? 1.f : (i == 1) ? -2.5f
                         : (i == 2) ? 2.f : -0.5f;
        const float zc3 = (i == 0) ? (-1.f / 6.f) : (i == 1) ? 0.5f
                         : (i == 2) ? -0.5f : (1.f / 6.f);
        const float zw   = zc0 + z * (zc1 + z * (zc2 + z * zc3));
        const float coef = zw * mm;

        const float pxf = (float)(h + n / 3) + ox;
        const float pyf = (float)(wcol + n % 3) + oy;
        const float flx = floorf(pxf), fly = floorf(pyf);
        const float qltx = fminf(fmaxf(flx, 0.f), 129.f);
        const float qrbx = fminf(fmaxf(flx + 1.f, 0.f), 129.f);
        const float qlty = fminf(fmaxf(fly, 0.f), 129.f);
        const float qrby = fminf(fmaxf(fly + 1.f, 0.f), 129.f);
        const float pxc = fminf(fmaxf(pxf, 0.f), 129.f);
        const float pyc = fminf(fmaxf(pyf, 0.f), 129.f);
        const float gxl = 1.f + (qltx - pxc);
        const float gxr = 1.f - (qrbx - pxc);
        const float gyl = 1.f + (qlty - pyc);
        const float gyr = 1.f - (qrby - pyc);
        const int ixl = (int)qltx, ixr = (int)qrbx;
        const int iyl = (int)qlty, iyr = (int)qrby;

        int4 ti; float4 tw;
        auto mk = [&](int qx, int qy, float g, int& ii, float& ww) {
            const bool valid = (qx >= 1) && (qx <= 128) && (qy >= 1) && (qy <= 128);
            ii = valid ? (((qx - 1) << 7) + (qy - 1)) : 0;
            ww = valid ? g * coef : 0.f;
        };
        mk(ixl, iyl, gxl * gyl, ti.x, tw.x);
        mk(ixr, iyr, gxr * gyr, ti.y, tw.y);
        mk(ixr, iyl, gxr * gyl, ti.z, tw.z);
        mk(ixl, iyr, gxl * gyr, ti.w, tw.w);
        s_ti4[u] = ti;
        s_tw4[u] = tw;
    }
    __syncthreads();

    // ---- phase B: sample s[px][c][n] ----
    const int c  = t & 63;
    const int wv = t >> 6;
    #pragma unroll 1
    for (int q = 0; q < 4; ++q) {
        const int px = (wv << 2) + q;
        float s[9];
        #pragma unroll
        for (int n = 0; n < 9; ++n) s[n] = 0.f;
        const int tb = px * 36;
        #pragma unroll
        for (int i = 0; i < 4; ++i) {
            const float* ib = imgT + ((((i << 1) + b) << 14) << 6) + c;
            #pragma unroll
            for (int n = 0; n < 9; ++n) {
                const int4   ti = s_ti4[tb + i * 9 + n];
                const float4 tw = s_tw4[tb + i * 9 + n];
                s[n] = fmaf(tw.x, ib[ti.x << 6], s[n]);
                s[n] = fmaf(tw.y, ib[ti.y << 6], s[n]);
                s[n] = fmaf(tw.z, ib[ti.z << 6], s[n]);
                s[n] = fmaf(tw.w, ib[ti.w << 6], s[n]);
            }
        }
        float* sp = s_s + px * 576 + c * 9;
        #pragma unroll
        for (int n = 0; n < 9; ++n) sp[n] = s[n];
    }
    __syncthreads();

    // ---- phase C: contraction out[o, px] ----
    const int o = t & 63;
    float acc0 = 0.f, acc1 = 0.f, acc2 = 0.f, acc3 = 0.f;
    const float* s0 = s_s + ((wv << 2) + 0) * 576;
    const float* s1 = s_s + ((wv << 2) + 1) * 576;
    const float* s2 = s_s + ((wv << 2) + 2) * 576;
    const float* s3 = s_s + ((wv << 2) + 3) * 576;
    #pragma unroll 2
    for (int cn = 0; cn < 576; cn += 4) {
        const float wv0 = WcT[(cn + 0) * 64 + o];
        const float wv1 = WcT[(cn + 1) * 64 + o];
        const float wv2 = WcT[(cn + 2) * 64 + o];
        const float wv3 = WcT[(cn + 3) * 64 + o];
        const float4 a = *(const float4*)(s0 + cn);
        const float4 e = *(const float4*)(s1 + cn);
        const float4 f = *(const float4*)(s2 + cn);
        const float4 g = *(const float4*)(s3 + cn);
        acc0 = fmaf(wv0, a.x, acc0); acc0 = fmaf(wv1, a.y, acc0);
        acc0 = fmaf(wv2, a.z, acc0); acc0 = fmaf(wv3, a.w, acc0);
        acc1 = fmaf(wv0, e.x, acc1); acc1 = fmaf(wv1, e.y, acc1);
        acc1 = fmaf(wv2, e.z, acc1); acc1 = fmaf(wv3, e.w, acc1);
        acc2 = fmaf(wv0, f.x, acc2); acc2 = fmaf(wv1, f.y, acc2);
        acc2 = fmaf(wv2, f.z, acc2); acc2 = fmaf(wv3, f.w, acc2);
        acc3 = fmaf(wv0, g.x, acc3); acc3 = fmaf(wv1, g.y, acc3);
        acc3 = fmaf(wv2, g.z, acc3); acc3 = fmaf(wv3, g.w, acc3);
    }

    // ---- phase D: staged coalesced store ----
    float* s_out = (float*)s_tw4;
    s_out[o * 17 + (wv << 2) + 0] = acc0;
    s_out[o * 17 + (wv << 2) + 1] = acc1;
    s_out[o * 17 + (wv << 2) + 2] = acc2;
    s_out[o * 17 + (wv << 2) + 3] = acc3;
    __syncthreads();
    #pragma unroll
    for (int k = 0; k < 4; ++k) {
        const int idx = t + (k << 8);
        const int oo  = idx >> 4;
        const int pxl = idx & 15;
        out[(((b << 6) + oo) << 14) + (h << 7) + w0p + pxl] = s_out[oo * 17 + pxl];
    }
}

// ---------------------------------------------------------------------------
extern "C" void kernel_launch(void* const* d_in, const int* in_sizes, int n_in,
                              void* d_out, int out_size, void* d_ws, size_t ws_size,
                              hipStream_t stream) {
    (void)in_sizes; (void)n_in; (void)out_size; (void)ws_size;
    const float* img1  = (const float*)d_in[0];
    const float* img2  = (const float*)d_in[1];
    const float* img4  = (const float*)d_in[2];
    const float* img5  = (const float*)d_in[3];
    const float* osrc  = (const float*)d_in[4];
    const float* w_pc1 = (const float*)d_in[5];
    const float* b_pc1 = (const float*)d_in[6];
    const float* w_pc2 = (const float*)d_in[7];
    const float* b_pc2 = (const float*)d_in[8];
    const float* w_pc4 = (const float*)d_in[9];
    const float* b_pc4 = (const float*)d_in[10];
    const float* w_pc5 = (const float*)d_in[11];
    const float* b_pc5 = (const float*)d_in[12];
    const float* w_z   = (const float*)d_in[13];
    const float* b_z   = (const float*)d_in[14];
    const float* w_m   = (const float*)d_in[15];
    const float* b_m   = (const float*)d_in[16];
    const float* w_cv  = (const float*)d_in[17];
    float* out = (float*)d_out;

    float* wsf  = (float*)d_ws;
    float* offs = wsf;                    // 4 * 589824 floats
    float* zbuf = wsf + 4 * 589824;       // 294912
    float* mbuf = zbuf + 294912;          // 294912
    float* WcT  = mbuf + 294912;          // 36864
    float* imgT = WcT + 36864;            // 8388608

    // Wpk/bpack/osT ALIAS the imgT region (conv pipeline finishes before
    // transpose_kernel overwrites imgT — same-stream serialization).
    __hip_bfloat16* Wpk   = (__hip_bfloat16*)imgT;            // 153600 bf16
    float*          bpack = imgT + 76800;                     // 96 f32
    __hip_bfloat16* osT   = (__hip_bfloat16*)(imgT + 76912);  // 2230272 bf16

    packw_kernel<<<dim3((96 * 1600 + 255) / 256), 256, 0, stream>>>(
        w_pc1, b_pc1, w_pc2, b_pc2, w_pc4, b_pc4, w_pc5, b_pc5,
        w_z, b_z, w_m, b_m, Wpk, bpack);
    packosT_kernel<<<dim3(132, 2), 256, 0, stream>>>(osrc, osT);
    conv_mfma_kernel<<<dim3(128, 2, 3), 256, 0, stream>>>(
        Wpk, bpack, osT, offs, zbuf, mbuf);
    transpose_kernel<<<dim3(256, 2, 4), 256, 0, stream>>>(img1, img2, img4, img5, imgT);
    wct_kernel<<<dim3(144), 256, 0, stream>>>(w_cv, WcT);
    fused_kernel<<<dim3(2048), 256, 0, stream>>>(offs, zbuf, mbuf, imgT, WcT, out);
}

// Round 5
// 192.563 us; speedup vs baseline: 4.3230x; 1.4556x over previous
//
#include <hip/hip_runtime.h>
#include <hip/hip_bf16.h>
#include <math.h>

#define HWX 16384   // 128*128 pixels per (b, channel) plane

typedef __attribute__((ext_vector_type(8))) short short8v;
typedef __attribute__((ext_vector_type(4))) float f32x4;

// ---------------------------------------------------------------------------
// Pack six 5x5-conv weight sets -> Wpk[oc][k] bf16, k = (ky*5+kx)*64 + ic.
//   oc 0..17 pc1 | 18..35 pc2 | 36..53 pc4 | 54..71 pc5 | 72..80 z | 81..89 m
//   | 90..95 zero.  bias fp32 in bpack[96].  Source OIHW: o*1600 + ic*25 + kyx.
// ---------------------------------------------------------------------------
__global__ __launch_bounds__(256) void packw_kernel(
    const float* __restrict__ w1, const float* __restrict__ b1,
    const float* __restrict__ w2, const float* __restrict__ b2,
    const float* __restrict__ w4, const float* __restrict__ b4,
    const float* __restrict__ w5, const float* __restrict__ b5,
    const float* __restrict__ wz, const float* __restrict__ bz,
    const float* __restrict__ wm, const float* __restrict__ bm,
    __hip_bfloat16* __restrict__ Wpk, float* __restrict__ bpack)
{
    const int idx = blockIdx.x * 256 + threadIdx.x;
    if (idx < 96) {
        const int o = idx; float v = 0.f;
        if      (o < 18) v = b1[o];
        else if (o < 36) v = b2[o - 18];
        else if (o < 54) v = b4[o - 36];
        else if (o < 72) v = b5[o - 54];
        else if (o < 81) v = bz[o - 72];
        else if (o < 90) v = bm[o - 81];
        bpack[o] = v;
    }
    if (idx < 96 * 1600) {
        const int o   = idx / 1600;
        const int k   = idx - o * 1600;
        const int kyx = k >> 6;
        const int ic  = k & 63;
        const int off = ic * 25 + kyx;
        float v = 0.f;
        if      (o < 18) v = w1[o * 1600 + off];
        else if (o < 36) v = w2[(o - 18) * 1600 + off];
        else if (o < 54) v = w4[(o - 36) * 1600 + off];
        else if (o < 72) v = w5[(o - 54) * 1600 + off];
        else if (o < 81) v = wz[(o - 72) * 1600 + off];
        else if (o < 90) v = wm[(o - 81) * 1600 + off];
        Wpk[idx] = __float2bfloat16(v);
    }
}

// ---------------------------------------------------------------------------
// offset_source -> channel-last bf16 with baked-in zero pad ring:
//   osT[b][yy:132][xx:132][c:64]
// ---------------------------------------------------------------------------
__global__ __launch_bounds__(256) void packosT_kernel(
    const float* __restrict__ src, __hip_bfloat16* __restrict__ osT)
{
    const int yy = blockIdx.x;
    const int b  = blockIdx.y;
    __hip_bfloat16* dst = osT + ((size_t)b * 132 + yy) * 132 * 64;
    for (int idx = threadIdx.x; idx < 132 * 64; idx += 256) {
        const int xx = idx >> 6;
        const int c  = idx & 63;
        float v = 0.f;
        if (yy >= 2 && yy < 130 && xx >= 2 && xx < 130)
            v = src[(((b << 6) + c) << 14) + ((yy - 2) << 7) + (xx - 2)];
        dst[idx] = __float2bfloat16(v);
    }
}

// ---------------------------------------------------------------------------
// MFMA conv: C[96][16384] = Wpk[96][1600] x im2col(osT), per batch.
// Pure-register MFMA, no LDS/barriers. Block 256 = 4 waves (32 oc x 32 px
// each); grid (128 rows, 2 b, 3 ocg).
// ---------------------------------------------------------------------------
__global__ __launch_bounds__(256) void conv_mfma_kernel(
    const __hip_bfloat16* __restrict__ Wpk,   // [96][1600]
    const float* __restrict__ bpack,          // [96]
    const __hip_bfloat16* __restrict__ osT,   // [2][132][132][64]
    float* __restrict__ offs,                 // [4][2][18][HWX]
    float* __restrict__ zbuf,                 // [2][9][HWX]
    float* __restrict__ mbuf)                 // [2][9][HWX]
{
    const int y   = blockIdx.x;
    const int b   = blockIdx.y;
    const int ocg = blockIdx.z;
    const int t    = threadIdx.x;
    const int wv   = t >> 6;
    const int lane = t & 63;
    const int l15  = lane & 15;
    const int kgrp = lane >> 4;

    const ushort* W  = (const ushort*)Wpk;
    const ushort* ob = (const ushort*)osT + (size_t)b * (132 * 132 * 64);

    const int aoff0 = (ocg * 32 + l15) * 1600 + kgrp * 8;
    const int aoff1 = aoff0 + 16 * 1600;
    const int xloc0 = wv * 32 + l15;
    const int boff0 = (y * 132 + xloc0) * 64 + kgrp * 8;
    const int boff1 = boff0 + 16 * 64;

    f32x4 acc00 = {0.f,0.f,0.f,0.f}, acc01 = {0.f,0.f,0.f,0.f};
    f32x4 acc10 = {0.f,0.f,0.f,0.f}, acc11 = {0.f,0.f,0.f,0.f};

    #pragma unroll
    for (int ky = 0; ky < 5; ++ky)
    #pragma unroll
    for (int kx = 0; kx < 5; ++kx)
    #pragma unroll
    for (int ics = 0; ics < 2; ++ics) {
        const int uA = ((ky * 5 + kx) << 6) + (ics << 5);
        const int uB = ((ky * 132 + kx) << 6) + (ics << 5);
        const short8v a0 = *(const short8v*)(W  + aoff0 + uA);
        const short8v a1 = *(const short8v*)(W  + aoff1 + uA);
        const short8v b0 = *(const short8v*)(ob + boff0 + uB);
        const short8v b1 = *(const short8v*)(ob + boff1 + uB);
        acc00 = __builtin_amdgcn_mfma_f32_16x16x32_bf16(a0, b0, acc00, 0, 0, 0);
        acc01 = __builtin_amdgcn_mfma_f32_16x16x32_bf16(a0, b1, acc01, 0, 0, 0);
        acc10 = __builtin_amdgcn_mfma_f32_16x16x32_bf16(a1, b0, acc10, 0, 0, 0);
        acc11 = __builtin_amdgcn_mfma_f32_16x16x32_bf16(a1, b1, acc11, 0, 0, 0);
    }

    const int rowb = kgrp << 2;
    #pragma unroll
    for (int m = 0; m < 2; ++m)
    #pragma unroll
    for (int nf = 0; nf < 2; ++nf)
    #pragma unroll
    for (int r = 0; r < 4; ++r) {
        const f32x4 acc = (m == 0) ? (nf == 0 ? acc00 : acc01)
                                   : (nf == 0 ? acc10 : acc11);
        const int oc = ocg * 32 + m * 16 + rowb + r;
        if (oc < 90) {
            const int x = wv * 32 + nf * 16 + l15;
            const int p = (y << 7) + x;
            const float v = acc[r] + bpack[oc];
            if (oc < 72) {
                const int i = oc / 18, ch = oc - i * 18;
                offs[i * (2 * 18 * HWX) + (((b * 18) + ch) << 14) + p] = v;
            } else if (oc < 81) {
                zbuf[((b * 9 + (oc - 72)) << 14) + p] = 3.f / (1.f + expf(-v));
            } else {
                mbuf[((b * 9 + (oc - 81)) << 14) + p] = 1.f / (1.f + expf(-v));
            }
        }
    }
}

// ---------------------------------------------------------------------------
// Transpose img[b,c,y,x] -> imgT[img][b][p][c]
// ---------------------------------------------------------------------------
__global__ __launch_bounds__(256) void transpose_kernel(
    const float* __restrict__ i0, const float* __restrict__ i1,
    const float* __restrict__ i2, const float* __restrict__ i3,
    float* __restrict__ imgT)
{
    const int img = blockIdx.z;
    const int b   = blockIdx.y;
    const int p0  = blockIdx.x << 6;
    const float* src = (img == 0) ? i0 : (img == 1) ? i1 : (img == 2) ? i2 : i3;

    __shared__ float tile[64][65];
    const int t = threadIdx.x;
    const int pp = t & 63, c0 = t >> 6;
    #pragma unroll
    for (int k = 0; k < 16; ++k) {
        const int c = (k << 2) + c0;
        tile[c][pp] = src[(((b << 6) + c) << 14) + p0 + pp];
    }
    __syncthreads();
    const int c = t & 63, pl = t >> 6;
    #pragma unroll
    for (int k = 0; k < 16; ++k) {
        const int pi = (k << 2) + pl;
        imgT[((((img << 1) + b) << 14) + p0 + pi) * 64 + c] = tile[c][pi];
    }
}

// ---------------------------------------------------------------------------
// WcPk = flat bf16 cast of w_conv[64][64][9]  (A-operand layout [oc][cn],
// cn = c*9+n, matches w_conv's natural flat order).
// ---------------------------------------------------------------------------
__global__ __launch_bounds__(256) void wcpk_kernel(
    const float* __restrict__ wc, __hip_bfloat16* __restrict__ WcPk)
{
    const int idx = blockIdx.x * 256 + threadIdx.x;
    if (idx < 36864) WcPk[idx] = __float2bfloat16(wc[idx]);
}

// ---------------------------------------------------------------------------
// Fused deform-sample + weighted-sum + MFMA contraction.
// One block = 16 consecutive pixels of one row of one batch.
//   A: 576 units -> tap indices + combined weights (LDS)
//   B: gather s[c][n] fp32, convert bf16 -> s_sb[16][584] (row-pad vs banks)
//   C: 4 waves x (16oc x 16px) MFMA, K=576: A=WcPk (global), B=s_sb (LDS)
// ---------------------------------------------------------------------------
__global__ __launch_bounds__(256) void fused_kernel(
    const float* __restrict__ offs,   // [4][2][18][HWX]
    const float* __restrict__ zbuf,   // [2][9][HWX]
    const float* __restrict__ mbuf,   // [2][9][HWX]
    const float* __restrict__ imgT,   // [4][2][HWX][64]
    const __hip_bfloat16* __restrict__ WcPk,  // [64][576]
    float* __restrict__ out)          // [2][64][HWX]
{
    __shared__ __hip_bfloat16 s_sb[16 * 584];   // 18688 B
    __shared__ int4   s_ti4[16 * 36];           // 9216 B
    __shared__ float4 s_tw4[16 * 36];           // 9216 B

    const int t   = threadIdx.x;
    const int pid = blockIdx.x;
    const int b   = pid >> 10;
    const int rem = pid & 1023;
    const int h   = rem >> 3;
    const int w0p = (rem & 7) << 4;

    // ---- phase A: taps ----
    for (int u = t; u < 576; u += 256) {
        const int px   = u / 36;
        const int unit = u - px * 36;
        const int i    = unit / 9;
        const int n    = unit - i * 9;
        const int wcol = w0p + px;
        const int p    = (h << 7) + wcol;

        const float* ob = offs + i * (2 * 18 * HWX) + ((b * 18) << 14);
        const float ox = ob[(n << 14) + p];
        const float oy = ob[((n + 9) << 14) + p];
        const float z  = zbuf[((b * 9 + n) << 14) + p];
        const float mm = mbuf[((b * 9 + n) << 14) + p];

        const float zc0 = (i == 0) ? 1.f : 0.f;
        const float zc1 = (i == 0) ? (-11.f / 6.f) : (i == 1) ? 3.f
                         : (i == 2) ? -1.5f : (1.f / 3.f);
        const float zc2 = (i == 0) ? 1.f : (i == 1) ? -2.5f
                         : (i == 2) ? 2.f : -0.5f;
        const float zc3 = (i == 0) ? (-1.f / 6.f) : (i == 1) ? 0.5f
                         : (i == 2) ? -0.5f : (1.f / 6.f);
        const float zw   = zc0 + z * (zc1 + z * (zc2 + z * zc3));
        const float coef = zw * mm;

        const float pxf = (float)(h + n / 3) + ox;
        const float pyf = (float)(wcol + n % 3) + oy;
        const float flx = floorf(pxf), fly = floorf(pyf);
        const float qltx = fminf(fmaxf(flx, 0.f), 129.f);
        const float qrbx = fminf(fmaxf(flx + 1.f, 0.f), 129.f);
        const float qlty = fminf(fmaxf(fly, 0.f), 129.f);
        const float qrby = fminf(fmaxf(fly + 1.f, 0.f), 129.f);
        const float pxc = fminf(fmaxf(pxf, 0.f), 129.f);
        const float pyc = fminf(fmaxf(pyf, 0.f), 129.f);
        const float gxl = 1.f + (qltx - pxc);
        const float gxr = 1.f - (qrbx - pxc);
        const float gyl = 1.f + (qlty - pyc);
        const float gyr = 1.f - (qrby - pyc);
        const int ixl = (int)qltx, ixr = (int)qrbx;
        const int iyl = (int)qlty, iyr = (int)qrby;

        int4 ti; float4 tw;
        auto mk = [&](int qx, int qy, float g, int& ii, float& ww) {
            const bool valid = (qx >= 1) && (qx <= 128) && (qy >= 1) && (qy <= 128);
            ii = valid ? (((qx - 1) << 7) + (qy - 1)) : 0;
            ww = valid ? g * coef : 0.f;
        };
        mk(ixl, iyl, gxl * gyl, ti.x, tw.x);
        mk(ixr, iyr, gxr * gyr, ti.y, tw.y);
        mk(ixr, iyl, gxr * gyl, ti.z, tw.z);
        mk(ixl, iyr, gxl * gyr, ti.w, tw.w);
        s_ti4[u] = ti;
        s_tw4[u] = tw;
    }
    __syncthreads();

    // ---- phase B: gather s[px][c][n], convert to bf16 in LDS ----
    const int c  = t & 63;
    const int wv = t >> 6;
    #pragma unroll 1
    for (int q = 0; q < 4; ++q) {
        const int px = (wv << 2) + q;
        float s[9];
        #pragma unroll
        for (int n = 0; n < 9; ++n) s[n] = 0.f;
        const int tb = px * 36;
        #pragma unroll
        for (int i = 0; i < 4; ++i) {
            const float* ib = imgT + ((((i << 1) + b) << 14) << 6) + c;
            #pragma unroll
            for (int n = 0; n < 9; ++n) {
                const int4   ti = s_ti4[tb + i * 9 + n];
                const float4 tw = s_tw4[tb + i * 9 + n];
                s[n] = fmaf(tw.x, ib[ti.x << 6], s[n]);
                s[n] = fmaf(tw.y, ib[ti.y << 6], s[n]);
                s[n] = fmaf(tw.z, ib[ti.z << 6], s[n]);
                s[n] = fmaf(tw.w, ib[ti.w << 6], s[n]);
            }
        }
        __hip_bfloat16* sp = s_sb + px * 584 + c * 9;
        #pragma unroll
        for (int n = 0; n < 9; ++n) sp[n] = __float2bfloat16(s[n]);
    }
    __syncthreads();

    // ---- phase C: MFMA contraction, wave wv -> oc block wv*16 ----
    const int lane = t & 63;
    const int l15  = lane & 15;
    const int kgrp = lane >> 4;
    const ushort* Wb = (const ushort*)WcPk + (wv * 16 + l15) * 576 + kgrp * 8;
    const ushort* sb = (const ushort*)s_sb + l15 * 584 + kgrp * 8;

    f32x4 acc = {0.f, 0.f, 0.f, 0.f};
    #pragma unroll
    for (int ks = 0; ks < 18; ++ks) {
        const short8v a  = *(const short8v*)(Wb + ks * 32);
        const short8v bb = *(const short8v*)(sb + ks * 32);
        acc = __builtin_amdgcn_mfma_f32_16x16x32_bf16(a, bb, acc, 0, 0, 0);
    }

    // store: oc = wv*16 + kgrp*4 + r, px = l15  (C/D: col=lane&15, row=...)
    const int p = (h << 7) + w0p + l15;
    #pragma unroll
    for (int r = 0; r < 4; ++r) {
        const int oc = wv * 16 + (kgrp << 2) + r;
        out[(((b << 6) + oc) << 14) + p] = acc[r];
    }
}

// ---------------------------------------------------------------------------
extern "C" void kernel_launch(void* const* d_in, const int* in_sizes, int n_in,
                              void* d_out, int out_size, void* d_ws, size_t ws_size,
                              hipStream_t stream) {
    (void)in_sizes; (void)n_in; (void)out_size; (void)ws_size;
    const float* img1  = (const float*)d_in[0];
    const float* img2  = (const float*)d_in[1];
    const float* img4  = (const float*)d_in[2];
    const float* img5  = (const float*)d_in[3];
    const float* osrc  = (const float*)d_in[4];
    const float* w_pc1 = (const float*)d_in[5];
    const float* b_pc1 = (const float*)d_in[6];
    const float* w_pc2 = (const float*)d_in[7];
    const float* b_pc2 = (const float*)d_in[8];
    const float* w_pc4 = (const float*)d_in[9];
    const float* b_pc4 = (const float*)d_in[10];
    const float* w_pc5 = (const float*)d_in[11];
    const float* b_pc5 = (const float*)d_in[12];
    const float* w_z   = (const float*)d_in[13];
    const float* b_z   = (const float*)d_in[14];
    const float* w_m   = (const float*)d_in[15];
    const float* b_m   = (const float*)d_in[16];
    const float* w_cv  = (const float*)d_in[17];
    float* out = (float*)d_out;

    float* wsf  = (float*)d_ws;
    float* offs = wsf;                    // 4 * 589824 floats
    float* zbuf = wsf + 4 * 589824;       // 294912
    float* mbuf = zbuf + 294912;          // 294912
    float* WcTr = mbuf + 294912;          // 36864 floats region (bf16 uses half)
    float* imgT = WcTr + 36864;           // 8388608

    __hip_bfloat16* WcPk = (__hip_bfloat16*)WcTr;

    // Wpk/bpack/osT ALIAS the imgT region (conv pipeline finishes before
    // transpose_kernel overwrites imgT — same-stream serialization).
    __hip_bfloat16* Wpk   = (__hip_bfloat16*)imgT;            // 153600 bf16
    float*          bpack = imgT + 76800;                     // 96 f32
    __hip_bfloat16* osT   = (__hip_bfloat16*)(imgT + 76912);  // 2230272 bf16

    packw_kernel<<<dim3((96 * 1600 + 255) / 256), 256, 0, stream>>>(
        w_pc1, b_pc1, w_pc2, b_pc2, w_pc4, b_pc4, w_pc5, b_pc5,
        w_z, b_z, w_m, b_m, Wpk, bpack);
    packosT_kernel<<<dim3(132, 2), 256, 0, stream>>>(osrc, osT);
    conv_mfma_kernel<<<dim3(128, 2, 3), 256, 0, stream>>>(
        Wpk, bpack, osT, offs, zbuf, mbuf);
    transpose_kernel<<<dim3(256, 2, 4), 256, 0, stream>>>(img1, img2, img4, img5, imgT);
    wcpk_kernel<<<dim3(144), 256, 0, stream>>>(w_cv, WcPk);
    fused_kernel<<<dim3(2048), 256, 0, stream>>>(offs, zbuf, mbuf, imgT, WcPk, out);
}